// Round 8
// baseline (343.987 us; speedup 1.0000x reference)
//
#include <hip/hip_runtime.h>

typedef unsigned long long u64;
typedef unsigned int u32;
typedef unsigned short u16;

#define N_ROIS   10000
#define N_CLS    151
#define PRE_TOPN 6000
#define POST_TOPN 300
#define MAX_PER  64
#define NMS_TH   0.3f
#define SCORE_TH 0.05f

#define BLOCKA   1024
#define NWAVES   16
#define BANDK    1536            // band-0 target: ~430 expected keeps >> 300 -> band 1 rare
#define BANDCAP  2048
#define CHUNK    512
#define CWORDS   16
#define TROWS    10240
#define NBINS    1024            // histogram bins = score bits >> 21

// ---- ws layout ----
#define WS_SROWS 80000           // u16[150*2048]  -> +614400 = 694400
#define WS_HDR   694400          // u32[150*8]     -> +4800   = 699200
#define WS_CUM   699200          // u32[150*1024]  -> +614400 = 1313600
#define WS_SCT   1313600         // f32[151*10240] -> +6184960 = 7498560
#define WS_NEED  7498560

// ---- select_kernel LDS ----
#define S_HIST_OFF 40000
#define S_KEYS_OFF 44096
#define S_RNK_OFF  60480
#define S_SMEM     68672

// ---- greedy_kernel LDS ----
#define G_SIDX_OFF  32768
#define G_SSC_OFF   40960
#define G_SUPP_OFF  49152        // union: keys2 u64[2048] @49152, rnk2 u32[2048] @65536
#define G_KEYS2_OFF 49152
#define G_RNK2_OFF  65536
#define G_KBOX_OFF  81920
#define G_CUM_OFF   86784
#define G_SBITS_OFF 90880
#define G_SMEM      130880

// IoU decision, IEEE f32 (no FMA contraction: could flip borderline iou<=0.3 vs XLA).
__device__ __forceinline__ bool suppresses(float4 a, float4 b)
{
#pragma clang fp contract(off)
    float areaa = (a.z - a.x + 1.f) * (a.w - a.y + 1.f);
    float areab = (b.z - b.x + 1.f) * (b.w - b.y + 1.f);
    float ix1 = fmaxf(a.x, b.x), iy1 = fmaxf(a.y, b.y);
    float ix2 = fminf(a.z, b.z), iy2 = fminf(a.w, b.w);
    float iw = fmaxf(ix2 - ix1 + 1.f, 0.f);
    float ih = fmaxf(iy2 - iy1 + 1.f, 0.f);
    float inter = iw * ih;
    float iou = inter / (areaa + areab - inter);
    return iou > NMS_TH;
}

// ======================= SELECT: column -> sorted top-band candidate rows =======================
__global__ __launch_bounds__(BLOCKA)
void select_kernel(const float* __restrict__ scores, const float* __restrict__ scoresT,
                   u16* __restrict__ srows, u32* __restrict__ hdr, u32* __restrict__ cumg,
                   int useT)
{
    extern __shared__ __align__(16) char smem[];
    __shared__ int s_cnts[32];
    __shared__ int s_cc, s_sel, s_resume;
    __shared__ u32 s_redu[NWAVES];
    __shared__ int s_wofs[NWAVES + 1];

    u32* sbits = (u32*)smem;
    u32* hist  = (u32*)(smem + S_HIST_OFF);
    u64* keys  = (u64*)(smem + S_KEYS_OFF);
    u32* rnk   = (u32*)(smem + S_RNK_OFF);

    const int c = blockIdx.x + 1, tid = threadIdx.x, lane = tid & 63, wid = tid >> 6;
    u32* myhdr = hdr + (size_t)blockIdx.x * 8;

    // load score-bit column + colmax; zero hist
    u32 lmax = 0;
    if (useT) {
        const float* colp = scoresT + (size_t)c * TROWS;
        for (int r = tid; r < N_ROIS; r += BLOCKA) { u32 b = __float_as_uint(colp[r]); sbits[r] = b; lmax = b > lmax ? b : lmax; }
    } else {
        for (int r = tid; r < N_ROIS; r += BLOCKA) { u32 b = __float_as_uint(scores[(size_t)r * N_CLS + c]); sbits[r] = b; lmax = b > lmax ? b : lmax; }
    }
    for (int off = 32; off; off >>= 1) { u32 o = __shfl_down(lmax, off); lmax = o > lmax ? o : lmax; }
    if (lane == 0) s_redu[wid] = lmax;
    if (tid < 32) s_cnts[tid] = 0;
    if (tid == 0) s_sel = 0;
    for (int b = tid; b < NBINS; b += BLOCKA) hist[b] = 0;
    __syncthreads();
    if (tid == 0) { u32 m = s_redu[0]; for (int w = 1; w < NWAVES; ++w) m = s_redu[w] > m ? s_redu[w] : m; s_redu[0] = m; }
    __syncthreads();
    if (s_redu[0] <= __float_as_uint(SCORE_TH)) { if (tid == 0) myhdr[0] = 0; return; }

    // histogram + suffix scan -> cum in hist[]
    for (int r = tid; r < N_ROIS; r += BLOCKA) atomicAdd(&hist[sbits[r] >> 21], 1u);
    __syncthreads();
    {
        u32* A = hist; u32* Bb = rnk;   // rnk reused as scratch (u32[1024] fits)
        for (int off = 1; off < NBINS; off <<= 1) {
            if (tid < NBINS) Bb[tid] = A[tid] + ((tid + off < NBINS) ? A[tid + off] : 0u);
            __syncthreads();
            u32* t = A; A = Bb; Bb = t;
        }
        if (A != hist) { if (tid < NBINS) hist[tid] = A[tid]; __syncthreads(); }
    }
    if (tid < NBINS) cumg[(size_t)blockIdx.x * NBINS + tid] = hist[tid];

    // B0 = largest bin with cum >= BANDK (cum monotone non-increasing -> count true bins)
    {
        bool pred = (tid < NBINS) && (hist[tid] >= (u32)BANDK);
        u64 ball = __ballot(pred);
        if (lane == 0 && ball) atomicAdd(&s_sel, (int)__popcll(ball));
    }
    __syncthreads();
    int B0 = s_sel - 1;                 // cum[0]=10000 >= 1536 -> B0 >= 0
    u32 V = (u32)B0 << 21; int cv = (int)hist[B0];

    int slot = 0;
    auto count_ge = [&](u32 v) -> int {
        int cnt = 0; const u64* sb2 = (const u64*)sbits;
        for (int r2 = tid; r2 < N_ROIS / 2; r2 += BLOCKA) {
            u64 two = sb2[r2];
            cnt += ((u32)two >= v) ? 1 : 0;
            cnt += ((u32)(two >> 32) >= v) ? 1 : 0;
        }
        for (int off = 32; off; off >>= 1) cnt += __shfl_down(cnt, off);
        if (lane == 0 && cnt) atomicAdd(&s_cnts[slot & 31], cnt);
        __syncthreads();
        int total = s_cnts[slot & 31];
        if (tid == 0) s_cnts[(slot + 16) & 31] = 0;
        ++slot; return total;
    };
    auto compactRange = [&](u32 vlo, u32 vhiX, int pos0) -> int {
        if (tid == 0) s_cc = 0;
        __syncthreads();
        for (int r = tid; r < TROWS; r += BLOCKA) {
            bool pred = (r < N_ROIS) && (sbits[r] >= vlo) && (sbits[r] < vhiX);
            u64 ball = __ballot(pred);
            int bpos = 0, bcnt = __popcll(ball);
            if (lane == 0 && bcnt) bpos = atomicAdd(&s_cc, bcnt);
            bpos = __shfl(bpos, 0);
            if (pred) {
                int pos = pos0 + bpos + (int)__popcll(ball & ((1ull << lane) - 1ull));
                if (pos < BANDCAP) keys[pos] = ((u64)sbits[r] << 32) | (u64)(0xFFFFFFFFu - (u32)r);
            }
        }
        __syncthreads(); return s_cc;
    };
    auto emitEq = [&](u32 v, int rowStart, int pos0, int capN, int* emittedOut) -> int {
        int run = 0, resume = N_ROIS;
        for (int r0 = 0; r0 < N_ROIS; r0 += BLOCKA) {
            if (r0 + BLOCKA <= rowStart) continue;
            int r = r0 + tid;
            bool pred = (r < N_ROIS) && (r >= rowStart) && (sbits[r] == v);
            u64 ball = __ballot(pred);
            if (lane == 0) s_wofs[wid] = __popcll(ball);
            __syncthreads();
            if (tid == 0) {
                int acc = 0;
                for (int w = 0; w < NWAVES; ++w) { int cw = s_wofs[w]; s_wofs[w] = acc; acc += cw; }
                s_wofs[NWAVES] = acc; s_resume = N_ROIS;
            }
            __syncthreads();
            int tot = s_wofs[NWAVES];
            if (pred) {
                int idx = run + s_wofs[wid] + (int)__popcll(ball & ((1ull << lane) - 1ull));
                if (idx < capN) keys[pos0 + idx] = ((u64)v << 32) | (u64)(0xFFFFFFFFu - (u32)r);
                else atomicMin(&s_resume, r);
            }
            __syncthreads();
            if (run + tot > capN) {
                resume = s_resume < (r0 + BLOCKA) ? s_resume : (r0 + BLOCKA);
                run = capN; break;
            }
            run += tot;
        }
        *emittedOut = run; return resume;
    };

    // rare: bin overshoot -> refine low 21 bits while over candidate capacity
    for (int b = 20; b >= 0 && cv > BANDCAP; --b) {
        u32 cd = V | (1u << b);
        int c2 = count_ge(cd);
        if (c2 >= BANDK) { V = cd; cv = c2; }
    }

    int C, procCnt, eqPend = 0, eqRow = N_ROIS; u32 Vhi = 0x80000000u, eqV = 0;
    if (cv > BANDCAP) {               // exact-value tie mass (astronomically rare): gt + eq stream
        int ngt = compactRange(V + 1, 0x80000000u, 0);
        int E; int resume = emitEq(V, 0, ngt, BANDCAP - ngt, &E);
        C = ngt + E; procCnt = C; eqV = V; eqRow = resume; eqPend = (resume < N_ROIS) ? 1 : 0;
        if (!eqPend) Vhi = V;
    } else {
        C = compactRange(V, 0x80000000u, 0);
        procCnt = cv; Vhi = V;
    }

    // exact rank (keys unique) + scatter sorted row ids
    for (int q = tid; q < BANDCAP; q += BLOCKA) rnk[q] = 0;
    __syncthreads();
    {
        int q0 = tid >> 1, par = tid & 1;
        for (int q = q0; q < C; q += BLOCKA / 2) {
            u64 kq = keys[q]; int partial = 0;
            for (int p = par; p < C; p += 2) partial += (keys[p] > kq) ? 1 : 0;
            atomicAdd(&rnk[q], (u32)partial);
        }
    }
    __syncthreads();
    for (int q = tid; q < C; q += BLOCKA) {
        u32 r = 0xFFFFFFFFu - (u32)keys[q];
        srows[(size_t)blockIdx.x * BANDCAP + rnk[q]] = (u16)r;
    }
    if (tid == 0) {
        myhdr[0] = 1; myhdr[1] = (u32)C; myhdr[2] = (u32)procCnt; myhdr[3] = Vhi;
        myhdr[4] = (u32)eqPend; myhdr[5] = eqV; myhdr[6] = (u32)eqRow; myhdr[7] = 0;
    }
}

// ======================= GREEDY: gather -> matrix -> fixpoint -> commit =======================
__global__ __launch_bounds__(BLOCKA)
void greedy_kernel(const float* __restrict__ scores, const float* __restrict__ scoresT,
                   const float* __restrict__ boxes,
                   const u16* __restrict__ srows, const u32* __restrict__ hdr,
                   const u32* __restrict__ cumg,
                   float* __restrict__ dists, u64* __restrict__ rowkey, int useT)
{
    extern __shared__ __align__(16) char smem[];
    __shared__ int s_cnts[32];
    __shared__ int s_cc, s_nk, s_chg, s_sel, s_resume;
    __shared__ u32 s_hd[8];
    __shared__ u32 s_alive[CWORDS], s_rz[CWORDS], s_K[CWORDS], s_Supp[CWORDS];
    __shared__ int s_wpre[CWORDS];
    __shared__ int s_wofs[NWAVES + 1];

    float4* sbox  = (float4*)smem;
    u32*    sidx  = (u32*)(smem + G_SIDX_OFF);
    u32*    ssc   = (u32*)(smem + G_SSC_OFF);
    u32*    supp  = (u32*)(smem + G_SUPP_OFF);
    u64*    keys2 = (u64*)(smem + G_KEYS2_OFF);
    u32*    rnk2  = (u32*)(smem + G_RNK2_OFF);
    float4* kbox  = (float4*)(smem + G_KBOX_OFF);
    u32*    cum   = (u32*)(smem + G_CUM_OFF);
    u32*    sbits = (u32*)(smem + G_SBITS_OFF);

    const int c = blockIdx.x + 1, tid = threadIdx.x, lane = tid & 63, wid = tid >> 6;

    if (tid < 8) s_hd[tid] = hdr[(size_t)blockIdx.x * 8 + tid];
    if (tid < 32) s_cnts[tid] = 0;
    if (tid == 0) s_nk = 0;
    // sbits always loaded (cheap, coalesced) - feeds ssc and the rare continuation
    if (useT) {
        const float* colp = scoresT + (size_t)c * TROWS;
        for (int r = tid; r < N_ROIS; r += BLOCKA) sbits[r] = __float_as_uint(colp[r]);
    } else {
        for (int r = tid; r < N_ROIS; r += BLOCKA) sbits[r] = __float_as_uint(scores[(size_t)r * N_CLS + c]);
    }
    if (tid < NBINS) cum[tid] = cumg[(size_t)blockIdx.x * NBINS + tid];
    __syncthreads();
    if (!s_hd[0]) return;
    int C = (int)s_hd[1];

    for (int i = tid; i < C; i += BLOCKA) {
        u32 r = (u32)srows[(size_t)blockIdx.x * BANDCAP + i];
        sidx[i] = r; ssc[i] = sbits[r];
        sbox[i] = *(const float4*)(boxes + ((size_t)r * N_CLS + c) * 4);
    }
    __syncthreads();

    auto runGreedy = [&](int Cb, int knumIn) -> int {
        int knum = knumIn;
        for (int base = 0; base < Cb && knum < POST_TOPN; base += CHUNK) {
            int chunkN = (Cb - base) < CHUNK ? (Cb - base) : CHUNK;
            int knum0 = knum;
            if (tid < CWORDS) {
                int rem = chunkN - tid * 32;
                s_alive[tid] = (rem <= 0) ? 0u : ((rem >= 32) ? 0xFFFFFFFFu : ((1u << rem) - 1u));
                s_rz[tid] = 0u;
            }
            for (int w = tid; w < CHUNK * CWORDS; w += BLOCKA) supp[w] = 0u;
            __syncthreads();
            if (knum0 > 0) {             // phase A: 2 threads per candidate vs kept list
                int cand = tid >> 1, half = tid & 1;
                if (cand < chunkN) {
                    float4 bq = sbox[base + cand];
                    for (int j = half; j < knum0; j += 2)
                        if (suppresses(kbox[j], bq)) { atomicAnd(&s_alive[cand >> 5], ~(1u << (cand & 31))); break; }
                }
                __syncthreads();
            }
            {   // pair matrix "p suppresses q" (p<q, both alive)
                int q0 = tid >> 1, par = tid & 1;
                for (int q = q0; q < chunkN; q += BLOCKA / 2) {
                    if (!((s_alive[q >> 5] >> (q & 31)) & 1u)) continue;
                    float4 bq = sbox[base + q];
                    for (int p = par; p < q; p += 2) {
                        if (!((s_alive[p >> 5] >> (p & 31)) & 1u)) continue;
                        if (suppresses(sbox[base + p], bq)) {
                            atomicOr(&supp[(p << 4) + (q >> 5)], 1u << (q & 31));
                            atomicOr(&s_rz[p >> 5], 1u << (p & 31));
                        }
                    }
                }
            }
            __syncthreads();
            if (tid < CWORDS) s_K[tid] = s_alive[tid];
            for (;;) {                   // Jacobi fixpoint (triangular -> converges, depth+1 iters)
                __syncthreads();
                if (tid < CWORDS) s_Supp[tid] = 0u;
                if (tid == 0) s_chg = 0;
                __syncthreads();
                for (int pw = tid; pw < (chunkN << 4); pw += BLOCKA) {
                    int p = pw >> 4, w = pw & 15;
                    if (((s_rz[p >> 5] >> (p & 31)) & 1u) && ((s_K[p >> 5] >> (p & 31)) & 1u)) {
                        u32 rw = supp[(p << 4) + w];
                        if (rw) atomicOr(&s_Supp[w], rw);
                    }
                }
                __syncthreads();
                if (tid < CWORDS) {
                    u32 nk = s_alive[tid] & ~s_Supp[tid];
                    if (nk != s_K[tid]) { s_K[tid] = nk; atomicOr(&s_chg, 1); }
                }
                __syncthreads();
                if (!s_chg) break;
            }
            if (wid == 0) {              // truncate to budget + word prefix
                u32 kw = (lane < CWORDS) ? s_K[lane] : 0u;
                int pc = __popc(kw);
                int inc = pc;
                for (int off = 1; off < 32; off <<= 1) { int o = __shfl_up(inc, off); if (lane >= off) inc += o; }
                int ex = inc - pc;
                int budget = POST_TOPN - knum0;
                u32 fin = kw;
                if (ex >= budget) fin = 0;
                else {
                    int need = budget - ex;
                    if (pc > need) { while (__popc(fin) > need) fin &= ~(1u << (31 - __clz(fin))); }
                }
                int pc2 = __popc(fin);
                int inc2 = pc2;
                for (int off = 1; off < 32; off <<= 1) { int o = __shfl_up(inc2, off); if (lane >= off) inc2 += o; }
                if (lane < CWORDS) { s_K[lane] = fin; s_wpre[lane] = inc2 - pc2; }
                if (lane == CWORDS - 1) s_nk = knum0 + inc2;
            }
            __syncthreads();
            if (tid < CHUNK) {           // commit
                int w = tid >> 5, b = tid & 31;
                u32 word = s_K[w];
                if ((word >> b) & 1u) {
                    int rank = knum0 + s_wpre[w] + __popc(word & ((1u << b) - 1u));
                    int q = base + tid;
                    u32 r = sidx[q], sb = ssc[q];
                    kbox[rank] = sbox[q];
                    dists[(size_t)r * N_CLS + c] = __uint_as_float(sb);
                    atomicMax(rowkey + r, ((u64)sb << 32) | (u64)(0xFFFFFFFFu - (u32)c));
                }
            }
            __syncthreads();
            knum = s_nk;
        }
        return knum;
    };

    int knum = runGreedy(C, 0);

    // ---- rare continuation (band 0 yielded < 300 keeps) ----
    if (knum < POST_TOPN) {
        int procCnt = (int)s_hd[2]; u32 Vhi = s_hd[3];
        int eqPend = (int)s_hd[4]; u32 eqV = s_hd[5]; int eqRow = (int)s_hd[6];
        bool haveFloor = false; u32 Vfloor = 0; int eligTotal = 0x7FFFFFFF;
        int slot = 0;
        auto count_ge = [&](u32 v) -> int {
            int cnt = 0; const u64* sb2 = (const u64*)sbits;
            for (int r2 = tid; r2 < N_ROIS / 2; r2 += BLOCKA) {
                u64 two = sb2[r2];
                cnt += ((u32)two >= v) ? 1 : 0;
                cnt += ((u32)(two >> 32) >= v) ? 1 : 0;
            }
            for (int off = 32; off; off >>= 1) cnt += __shfl_down(cnt, off);
            if (lane == 0 && cnt) atomicAdd(&s_cnts[slot & 31], cnt);
            __syncthreads();
            int total = s_cnts[slot & 31];
            if (tid == 0) s_cnts[(slot + 16) & 31] = 0;
            ++slot; return total;
        };
        auto compactRange = [&](u32 vlo, u32 vhiX, int pos0) -> int {
            if (tid == 0) s_cc = 0;
            __syncthreads();
            for (int r = tid; r < TROWS; r += BLOCKA) {
                bool pred = (r < N_ROIS) && (sbits[r] >= vlo) && (sbits[r] < vhiX);
                u64 ball = __ballot(pred);
                int bpos = 0, bcnt = __popcll(ball);
                if (lane == 0 && bcnt) bpos = atomicAdd(&s_cc, bcnt);
                bpos = __shfl(bpos, 0);
                if (pred) {
                    int pos = pos0 + bpos + (int)__popcll(ball & ((1ull << lane) - 1ull));
                    if (pos < BANDCAP) keys2[pos] = ((u64)sbits[r] << 32) | (u64)(0xFFFFFFFFu - (u32)r);
                }
            }
            __syncthreads(); return s_cc;
        };
        auto emitEq = [&](u32 v, int rowStart, int pos0, int capN, int* emittedOut) -> int {
            int run = 0, resume = N_ROIS;
            for (int r0 = 0; r0 < N_ROIS; r0 += BLOCKA) {
                if (r0 + BLOCKA <= rowStart) continue;
                int r = r0 + tid;
                bool pred = (r < N_ROIS) && (r >= rowStart) && (sbits[r] == v);
                u64 ball = __ballot(pred);
                if (lane == 0) s_wofs[wid] = __popcll(ball);
                __syncthreads();
                if (tid == 0) {
                    int acc = 0;
                    for (int w = 0; w < NWAVES; ++w) { int cw = s_wofs[w]; s_wofs[w] = acc; acc += cw; }
                    s_wofs[NWAVES] = acc; s_resume = N_ROIS;
                }
                __syncthreads();
                int tot = s_wofs[NWAVES];
                if (pred) {
                    int idx = run + s_wofs[wid] + (int)__popcll(ball & ((1ull << lane) - 1ull));
                    if (idx < capN) keys2[pos0 + idx] = ((u64)v << 32) | (u64)(0xFFFFFFFFu - (u32)r);
                    else atomicMin(&s_resume, r);
                }
                __syncthreads();
                if (run + tot > capN) {
                    resume = s_resume < (r0 + BLOCKA) ? s_resume : (r0 + BLOCKA);
                    run = capN; break;
                }
                run += tot;
            }
            *emittedOut = run; return resume;
        };

        for (int band = 0; band < 64 && knum < POST_TOPN; ++band) {
            int Cb = 0;
            if (eqPend) {
                int E; int resume = emitEq(eqV, eqRow, 0, BANDCAP, &E);
                Cb = E; procCnt += E;
                if (resume >= N_ROIS) { eqPend = 0; Vhi = eqV; }
                eqRow = resume;
                if (Cb == 0) { if (eqPend) break; else continue; }
            } else {
                if (!haveFloor) {
                    u32 Vf = 0; int cvf = N_ROIS;
                    for (int b = 30; b >= 0; --b) {
                        u32 cd = Vf | (1u << b);
                        int c2 = count_ge(cd);
                        if (c2 >= PRE_TOPN) { Vf = cd; cvf = c2; }
                    }
                    Vfloor = Vf; eligTotal = cvf; haveFloor = true;
                }
                if (procCnt >= eligTotal) break;
                int target = procCnt + BANDK, capAbs = procCnt + BANDCAP;
                if (tid == 0) s_sel = 0;
                __syncthreads();
                {
                    bool pred = (tid < NBINS) && (cum[tid] >= (u32)target);
                    u64 ball = __ballot(pred);
                    if (lane == 0 && ball) atomicAdd(&s_sel, (int)__popcll(ball));
                }
                __syncthreads();
                int nb = s_sel;
                u32 V; int cv2;
                if (nb <= 0) { V = 0u; cv2 = (int)cum[0]; }
                else { V = (u32)(nb - 1) << 21; cv2 = (int)cum[nb - 1]; }
                for (int b = 20; b >= 0 && cv2 > capAbs; --b) {
                    u32 cd = V | (1u << b);
                    int c2 = count_ge(cd);
                    if (c2 >= target) { V = cd; cv2 = c2; }
                }
                if (haveFloor && V < Vfloor) { V = Vfloor; cv2 = eligTotal; }
                if (cv2 > capAbs) {
                    int ngt = compactRange(V + 1, Vhi, 0);
                    int E; int resume = emitEq(V, 0, ngt, BANDCAP - ngt, &E);
                    Cb = ngt + E; procCnt += Cb; eqV = V; eqRow = resume; eqPend = (resume < N_ROIS) ? 1 : 0;
                    if (!eqPend) Vhi = V;
                } else {
                    Cb = compactRange(V, Vhi, 0); procCnt = cv2; Vhi = V;
                }
                if (Cb <= 0) continue;
            }
            // rank + scatter/gather into sbox/sidx/ssc
            for (int q = tid; q < BANDCAP; q += BLOCKA) rnk2[q] = 0;
            __syncthreads();
            {
                int q0 = tid >> 1, par = tid & 1;
                for (int q = q0; q < Cb; q += BLOCKA / 2) {
                    u64 kq = keys2[q]; int partial = 0;
                    for (int p = par; p < Cb; p += 2) partial += (keys2[p] > kq) ? 1 : 0;
                    atomicAdd(&rnk2[q], (u32)partial);
                }
            }
            __syncthreads();
            for (int q = tid; q < Cb; q += BLOCKA) {
                u64 kq = keys2[q]; u32 pos = rnk2[q]; u32 r = 0xFFFFFFFFu - (u32)kq;
                sidx[pos] = r; ssc[pos] = (u32)(kq >> 32);
                sbox[pos] = *(const float4*)(boxes + ((size_t)r * N_CLS + c) * 4);
            }
            __syncthreads();
            knum = runGreedy(Cb, knum);
        }
    }
}

// fused: scores transpose + zero dists/rowkey
__global__ __launch_bounds__(1024)
void transpose_zero_kernel(const float* __restrict__ in, float* __restrict__ outT,
                           float* __restrict__ dists, u64* __restrict__ rowkey, int useT)
{
    __shared__ float tile[32][33];
    if (useT) {
        int tx = threadIdx.x & 31, ty = threadIdx.x >> 5;
        int rb = blockIdx.x * 32, cb = blockIdx.y * 32;
        int r = rb + ty, cc = cb + tx;
        tile[ty][tx] = (r < N_ROIS && cc < N_CLS) ? in[(size_t)r * N_CLS + cc] : 0.f;
        __syncthreads();
        int oc = cb + ty, orr = rb + tx;
        if (oc < N_CLS) outT[(size_t)oc * TROWS + orr] = tile[tx][ty];
    }
    int bid = blockIdx.y * gridDim.x + blockIdx.x;
    int flat = bid * 1024 + threadIdx.x;
    if (flat < N_ROIS * N_CLS) dists[flat] = 0.f;
    if (flat < N_ROIS) rowkey[flat] = 0ull;
}

// top-64 (R6-validated)
__global__ __launch_bounds__(BLOCKA)
void topk_kernel(const u64* __restrict__ rowkey, float* __restrict__ out)
{
    __shared__ u32 shi[N_ROIS];
    __shared__ int s_cnts[32];
    __shared__ int s_cc;
    __shared__ u64 cand[192];
    __shared__ int s_wofs[NWAVES + 1];
    const int tid = threadIdx.x, lane = tid & 63, wid = tid >> 6;

    if (tid < 32) s_cnts[tid] = 0;
    if (tid == 0) s_cc = 0;
    if (tid < 192) cand[tid] = 0;
    for (int i = tid; i < N_ROIS; i += BLOCKA) {
        u64 rk = rowkey[i];
        u32 hb = (u32)(rk >> 32);
        shi[i] = (__uint_as_float(hb) > SCORE_TH) ? hb : 0u;
    }
    __syncthreads();

    int slot = 0;
    auto count_ge = [&](u32 v) -> int {
        int cnt = 0; const u64* s2 = (const u64*)shi;
        for (int r2 = tid; r2 < N_ROIS / 2; r2 += BLOCKA) {
            u64 two = s2[r2];
            cnt += ((u32)two >= v) ? 1 : 0;
            cnt += ((u32)(two >> 32) >= v) ? 1 : 0;
        }
        for (int off = 32; off; off >>= 1) cnt += __shfl_down(cnt, off);
        if (lane == 0 && cnt) atomicAdd(&s_cnts[slot & 31], cnt);
        __syncthreads();
        int total = s_cnts[slot & 31];
        if (tid == 0) s_cnts[(slot + 16) & 31] = 0;
        ++slot; return total;
    };

    const int cap = 128;
    u32 V = 0; int cv = N_ROIS;
    for (int b = 30; b >= 16; --b) {
        u32 cd = V | (1u << b);
        int c2 = count_ge(cd);
        if (c2 >= MAX_PER) { V = cd; cv = c2; }
    }
    for (int b = 15; b >= 0 && cv > cap; --b) {
        u32 cd = V | (1u << b);
        int c2 = count_ge(cd);
        if (c2 >= MAX_PER) { V = cd; cv = c2; }
    }
    if (V == 0) { V = 1; cv = count_ge(1); }
    int C = 0;
    if (cv > cap) {
        if (tid == 0) s_cc = 0;
        __syncthreads();
        for (int i = tid; i < TROWS; i += BLOCKA) {
            bool pred = (i < N_ROIS) && (shi[i] >= V + 1);
            u64 ball = __ballot(pred);
            int bpos = 0, bcnt = __popcll(ball);
            if (lane == 0 && bcnt) bpos = atomicAdd(&s_cc, bcnt);
            bpos = __shfl(bpos, 0);
            if (pred) {
                int pos = bpos + (int)__popcll(ball & ((1ull << lane) - 1ull));
                if (pos < cap) cand[pos] = ((u64)shi[i] << 32) | (u64)(0xFFFFFFFFu - (u32)i);
            }
        }
        __syncthreads();
        int ngt = s_cc; if (ngt > cap) ngt = cap;
        int need = MAX_PER - ngt;
        int run = 0;
        for (int r0 = 0; r0 < N_ROIS && run < need; r0 += BLOCKA) {
            int r = r0 + tid;
            bool pred = (r < N_ROIS) && (shi[r] == V);
            u64 ball = __ballot(pred);
            if (lane == 0) s_wofs[wid] = __popcll(ball);
            __syncthreads();
            if (tid == 0) {
                int acc = 0;
                for (int w = 0; w < NWAVES; ++w) { int cw = s_wofs[w]; s_wofs[w] = acc; acc += cw; }
                s_wofs[NWAVES] = acc;
            }
            __syncthreads();
            int tot = s_wofs[NWAVES];
            if (pred) {
                int idx = run + s_wofs[wid] + (int)__popcll(ball & ((1ull << lane) - 1ull));
                if (idx < need) cand[ngt + idx] = ((u64)V << 32) | (u64)(0xFFFFFFFFu - (u32)r);
            }
            __syncthreads();
            run += tot;
        }
        C = ngt + (run < need ? run : need);
    } else {
        if (tid == 0) s_cc = 0;
        __syncthreads();
        for (int i = tid; i < TROWS; i += BLOCKA) {
            bool pred = (i < N_ROIS) && (shi[i] >= V);
            u64 ball = __ballot(pred);
            int bpos = 0, bcnt = __popcll(ball);
            if (lane == 0 && bcnt) bpos = atomicAdd(&s_cc, bcnt);
            bpos = __shfl(bpos, 0);
            if (pred) {
                int pos = bpos + (int)__popcll(ball & ((1ull << lane) - 1ull));
                if (pos < cap) cand[pos] = ((u64)shi[i] << 32) | (u64)(0xFFFFFFFFu - (u32)i);
            }
        }
        __syncthreads();
        C = s_cc; if (C > cap) C = cap;
    }

    float* out_s = out + (size_t)N_ROIS * N_CLS;
    float* out_i = out_s + MAX_PER;
    float* out_l = out_i + MAX_PER;

    int myrank = -1; u64 myk = 0;
    if (tid < C) {
        myk = cand[tid];
        myrank = 0;
        for (int p = 0; p < C; ++p) myrank += (cand[p] > myk) ? 1 : 0;
    }
    if (tid < MAX_PER) { out_s[tid] = 0.f; out_i[tid] = -1.f; out_l[tid] = -1.f; }
    __syncthreads();
    if (tid < C && myrank < MAX_PER) {
        u32 r = 0xFFFFFFFFu - (u32)myk;
        out_s[myrank] = __uint_as_float((u32)(myk >> 32));
        out_i[myrank] = (float)r;
        out_l[myrank] = (float)(0xFFFFFFFFu - (u32)rowkey[r]);
    }
}

extern "C" void kernel_launch(void* const* d_in, const int* in_sizes, int n_in,
                              void* d_out, int out_size, void* d_ws, size_t ws_size,
                              hipStream_t stream)
{
    const float* scores = (const float*)d_in[0];  // [10000, 151] f32
    const float* boxes  = (const float*)d_in[1];  // [10000, 151, 4] f32
    float* out = (float*)d_out;                   // dists | scores[64] | inds[64] | labels[64]

    u64* rowkey  = (u64*)d_ws;
    u16* srows   = (u16*)((char*)d_ws + WS_SROWS);
    u32* hdr     = (u32*)((char*)d_ws + WS_HDR);
    u32* cumg    = (u32*)((char*)d_ws + WS_CUM);
    float* scoresT = (float*)((char*)d_ws + WS_SCT);
    int useT = (ws_size >= (size_t)WS_NEED) ? 1 : 0;

    (void)hipFuncSetAttribute((const void*)select_kernel,
                              hipFuncAttributeMaxDynamicSharedMemorySize, S_SMEM);
    (void)hipFuncSetAttribute((const void*)greedy_kernel,
                              hipFuncAttributeMaxDynamicSharedMemorySize, G_SMEM);

    transpose_zero_kernel<<<dim3(320, 5), 1024, 0, stream>>>(scores, scoresT, out, rowkey, useT);
    select_kernel<<<N_CLS - 1, BLOCKA, S_SMEM, stream>>>(scores, scoresT, srows, hdr, cumg, useT);
    greedy_kernel<<<N_CLS - 1, BLOCKA, G_SMEM, stream>>>(scores, scoresT, boxes, srows, hdr, cumg, out, rowkey, useT);
    topk_kernel<<<1, BLOCKA, 0, stream>>>(rowkey, out);
}